// Round 7
// baseline (259.685 us; speedup 1.0000x reference)
//
#include <hip/hip_runtime.h>

#define NROWS 4096
#define LV 128
#define H 256
#define D 256
#define LN_EPS 1e-5f

typedef __attribute__((ext_vector_type(4))) float  f32x4;
typedef __attribute__((ext_vector_type(8))) short  bf16x8;

__device__ __forceinline__ short f2bf(float f) {
    union { float f; unsigned u; } a; a.f = f;
    unsigned r = a.u + 0x7FFFu + ((a.u >> 16) & 1u);
    return (short)(r >> 16);
}

// ---- kernel 1: W_in||W_h (1024x256 f32) -> MFMA B-fragment-ordered bf16 in ws ----
// frag fid = nt*32 + t : 64 lanes x 8 bf16.  lane l holds B[k=t*32+(l>>4)*8+e][col=nt*16+(l&15)]
__global__ __launch_bounds__(256) void wconv(
    const float* __restrict__ W_in, const float* __restrict__ W_h,
    short* __restrict__ wsb)
{
    const int fid = blockIdx.x * 4 + (threadIdx.x >> 6);  // 0..511
    const int l   = threadIdx.x & 63;
    const int nt  = fid >> 5, t = fid & 31;
    const int col = nt * 16 + (l & 15);
    const int k0  = t * 32 + (l >> 4) * 8;
    bf16x8 o;
#pragma unroll
    for (int e = 0; e < 8; e++) {
        int k = k0 + e;
        float x = (k < 768) ? W_in[(size_t)k * H + col] : W_h[(size_t)(k - 768) * H + col];
        o[e] = f2bf(x);
    }
    *(bf16x8*)&wsb[(size_t)fid * 512 + l * 8] = o;
}

// ---- kernel 2: standalone MFMA compute; 1 wave per block, 16 rows per wave ----
__global__ __launch_bounds__(64) void coord_compute(
    const float* __restrict__ memory,
    const int*   __restrict__ veh_idx,
    const float* __restrict__ veh_repr,
    const float* __restrict__ cust_repr,
    const float* __restrict__ edge_emb,
    const float* __restrict__ b_in,
    const float* __restrict__ b_h,
    const float* __restrict__ gamma,
    const float* __restrict__ beta,
    const short* __restrict__ wsb,
    float* __restrict__ out)
{
    const int l     = threadIdx.x & 63;
    const int row0w = blockIdx.x * 16;            // this wave's first row

    // A-operand: lane l holds A[row=l&15][k=(l>>4)*8 + e] per k-step
    const int arow = row0w + (l & 15);
    const int kg8  = (l >> 4) * 8;
    const int idxA = veh_idx[arow];

    const float* pV = veh_repr  + (size_t)arow * D + kg8;
    const float* pC = cust_repr + (size_t)arow * D + kg8;
    const float* pE = edge_emb  + (size_t)arow * D + kg8;
    const float* pM = memory + (size_t)arow * LV * H + (size_t)idxA * H + kg8;

    f32x4 acc[16];
#pragma unroll
    for (int nt = 0; nt < 16; nt++) acc[nt] = (f32x4){0.f, 0.f, 0.f, 0.f};

#define DO_SEG(BASE, T0)                                                        \
    _Pragma("unroll")                                                           \
    for (int tt = 0; tt < 8; tt++) {                                            \
        const int t = (T0) + tt;                                                \
        f32x4 xa = *(const f32x4*)((BASE) + tt * 32);                           \
        f32x4 xb = *(const f32x4*)((BASE) + tt * 32 + 4);                       \
        bf16x8 afrag;                                                           \
        afrag[0] = f2bf(xa[0]); afrag[1] = f2bf(xa[1]);                         \
        afrag[2] = f2bf(xa[2]); afrag[3] = f2bf(xa[3]);                         \
        afrag[4] = f2bf(xb[0]); afrag[5] = f2bf(xb[1]);                         \
        afrag[6] = f2bf(xb[2]); afrag[7] = f2bf(xb[3]);                         \
        _Pragma("unroll")                                                       \
        for (int nt = 0; nt < 16; nt++) {                                       \
            bf16x8 bfrag = *(const bf16x8*)&wsb[(size_t)(nt * 32 + t) * 512 + l * 8]; \
            acc[nt] = __builtin_amdgcn_mfma_f32_16x16x32_bf16(afrag, bfrag, acc[nt], 0, 0, 0); \
        }                                                                       \
    }

    DO_SEG(pV, 0)
    DO_SEG(pC, 8)
    DO_SEG(pE, 16)
    DO_SEG(pM, 24)
#undef DO_SEG

    // C/D layout: col = nt*16 + (l&15), row = (l>>4)*4 + i
    const int c_lo = l & 15;

#pragma unroll
    for (int nt = 0; nt < 16; nt++) {
        float bsum = b_in[nt * 16 + c_lo] + b_h[nt * 16 + c_lo];
#pragma unroll
        for (int i = 0; i < 4; i++) acc[nt][i] += bsum;
    }

    // LayerNorm per row: reduce over 16 nt (in-lane) then 16 lanes (butterfly)
    float s[4] = {0.f, 0.f, 0.f, 0.f}, q[4] = {0.f, 0.f, 0.f, 0.f};
#pragma unroll
    for (int nt = 0; nt < 16; nt++)
#pragma unroll
        for (int i = 0; i < 4; i++) {
            float v = acc[nt][i];
            s[i] += v; q[i] += v * v;
        }
#pragma unroll
    for (int off = 1; off < 16; off <<= 1)
#pragma unroll
        for (int i = 0; i < 4; i++) {
            s[i] += __shfl_xor(s[i], off);
            q[i] += __shfl_xor(q[i], off);
        }

    float mu[4], rs[4];
#pragma unroll
    for (int i = 0; i < 4; i++) {
        mu[i] = s[i] * (1.f / H);
        rs[i] = rsqrtf(q[i] * (1.f / H) - mu[i] * mu[i] + LN_EPS);
    }

#pragma unroll
    for (int i = 0; i < 4; i++) {
        const int grow = row0w + (l >> 4) * 4 + i;
        const int idxC = veh_idx[grow];
        float* po = out + (size_t)grow * LV * H + (size_t)idxC * H + c_lo;
#pragma unroll
        for (int nt = 0; nt < 16; nt++) {
            float g  = gamma[nt * 16 + c_lo];
            float be = beta[nt * 16 + c_lo];
            float ln = (acc[nt][i] - mu[i]) * rs[i] * g + be;
            po[nt * 16] = tanhf(ln);
        }
    }
}

extern "C" void kernel_launch(void* const* d_in, const int* in_sizes, int n_in,
                              void* d_out, int out_size, void* d_ws, size_t ws_size,
                              hipStream_t stream) {
    const float* memory    = (const float*)d_in[0];
    const int*   veh_idx   = (const int*)d_in[1];
    const float* veh_repr  = (const float*)d_in[2];
    const float* cust_repr = (const float*)d_in[3];
    const float* edge_emb  = (const float*)d_in[4];
    const float* W_in      = (const float*)d_in[5];
    const float* b_in      = (const float*)d_in[6];
    const float* W_h       = (const float*)d_in[7];
    const float* b_h       = (const float*)d_in[8];
    const float* gamma     = (const float*)d_in[9];
    const float* beta      = (const float*)d_in[10];
    float* out = (float*)d_out;
    short* wsb = (short*)d_ws;   // 512 KB of B-fragments

    // 1) weight pre-pass (independent of memcpy, tiny)
    wconv<<<128, 256, 0, stream>>>(W_in, W_h, wsb);

    // 2) bulk copy at rocclr-copy speed (~6.3 TB/s measured in this harness)
    const size_t bytes = (size_t)NROWS * LV * H * sizeof(float);
    hipMemcpyAsync(d_out, d_in[0], bytes, hipMemcpyDeviceToDevice, stream);

    // 3) overwrite the (n, idx[n]) rows with the computed update
    coord_compute<<<NROWS / 16, 64, 0, stream>>>(
        memory, veh_idx, veh_repr, cust_repr, edge_emb,
        b_in, b_h, gamma, beta, wsb, out);
}